// Round 4
// baseline (1833.631 us; speedup 1.0000x reference)
//
#include <hip/hip_runtime.h>

#define NB 64
#define NT 4096
#define ND 32
#define NH 128
#define SC 32                    // steps per sub-chunk
#define NSC (NT / SC)            // 128 sub-chunks

typedef _Float16 half8 __attribute__((ext_vector_type(8)));
typedef float floatx4 __attribute__((ext_vector_type(4)));

// s_barrier WITHOUT vmcnt drain: orders LDS only (all cross-wave data is LDS).
// Lets u-prefetch global loads stay in flight across step barriers.
__device__ __forceinline__ void wg_barrier() {
    asm volatile("s_waitcnt lgkmcnt(0)\n\ts_barrier" ::: "memory");
}

// constant-indexed 4:1 mux
__device__ __forceinline__ float sel4(floatx4 v, bool b0, bool b1) {
    float s0 = b0 ? v[1] : v[0];
    float s1 = b0 ? v[3] : v[2];
    return b1 ? s1 : s0;
}

// One workgroup (256 thr = 4 waves) per batch sample. Wave w owns hidden rows
// [32w, 32w+32) as two 16-row groups. Per round: 5 ds_read_b128 (4x h + 1x u)
// -> 30 MFMA (r/z: K=160 fused [h;u] 5-deep; n: K=128 h-chain + K=32 xn)
// -> per-lane gate unit (group=(cl>>2)&1, unit=cl&3) -> 1 ds_write_b16 -> barrier.
// Weights prescaled: r/z by -log2e (sigmoid = rcp(1+exp2(s))),
//                    n   by 2*log2e (tanh = 1-2*rcp(1+exp2(s))).
__global__ void __launch_bounds__(256, 1) gru_fused_kernel(
    const float* __restrict__ u,
    const float* __restrict__ w_ih,
    const float* __restrict__ w_hh,
    const float* __restrict__ b_ih,
    const float* __restrict__ b_hh,
    const float* __restrict__ fc_w,
    const float* __restrict__ fc_b,
    float* __restrict__ out)
{
    __shared__ __align__(16) _Float16 hhist[(SC + 1) * NH];   // 8.25 KB h history
    __shared__ __align__(16) _Float16 u16[SC * ND];           // 2 KB f16 input sub-chunk
    __shared__ float fcw_lds[NH];                             // 0.5 KB

    const int tid = (int)threadIdx.x;
    const int b   = (int)blockIdx.x;
    const int w   = tid >> 6;   // wave 0..3
    const int l   = tid & 63;   // lane
    const int q   = l >> 4;     // lane quad-group 0..3
    const int cl  = l & 15;     // A-row / B-col / C-col within tile
    const int jb  = w * 32;     // this wave's hidden-row base (2 groups of 16)
    const bool s0 = (cl & 1) != 0;   // gate-unit select (unit = cl&3)
    const bool s1 = (cl & 2) != 0;
    const bool gs = (cl & 4) != 0;   // row-group select

    const float dsc = -1.44269504089f;  // -log2(e)
    const float csc =  2.88539008178f;  // 2*log2(e)

    // ---- weight A-fragments, prescaled. A[row=cl][k=q*8+i within chunk] ----
    // Per group G: aR[G][0..3] = W_hr k-chunks, aR[G][4] = W_ir (K=32 u-part);
    //              aZ likewise; aN[G][0..3] = W_hn; aX[G] = W_in.
    half8 aR[2][5], aZ[2][5], aN[2][4], aX[2];
    #pragma unroll
    for (int G = 0; G < 2; ++G) {
        const int jbg = jb + G * 16;
        #pragma unroll
        for (int c = 0; c < 4; ++c) {
            const float* pr = w_hh + (size_t)(0 * NH + jbg + cl) * NH + c * 32 + q * 8;
            const float* pz = w_hh + (size_t)(1 * NH + jbg + cl) * NH + c * 32 + q * 8;
            const float* pn = w_hh + (size_t)(2 * NH + jbg + cl) * NH + c * 32 + q * 8;
            #pragma unroll
            for (int i = 0; i < 8; ++i) {
                aR[G][c][i] = (_Float16)(dsc * pr[i]);
                aZ[G][c][i] = (_Float16)(dsc * pz[i]);
                aN[G][c][i] = (_Float16)(csc * pn[i]);
            }
        }
        const float* pr = w_ih + (size_t)(0 * NH + jbg + cl) * ND + q * 8;
        const float* pz = w_ih + (size_t)(1 * NH + jbg + cl) * ND + q * 8;
        const float* pn = w_ih + (size_t)(2 * NH + jbg + cl) * ND + q * 8;
        #pragma unroll
        for (int i = 0; i < 8; ++i) {
            aR[G][4][i] = (_Float16)(dsc * pr[i]);
            aZ[G][4][i] = (_Float16)(dsc * pz[i]);
            aX[G][i]    = (_Float16)(csc * pn[i]);
        }
    }

    // Prescaled bias quads (C rows j = jbg + q*4 + i).
    floatx4 rbv[2], zbv[2], xbv[2], hbv[2];
    #pragma unroll
    for (int G = 0; G < 2; ++G) {
        #pragma unroll
        for (int i = 0; i < 4; ++i) {
            const int j = jb + G * 16 + q * 4 + i;
            rbv[G][i] = dsc * (b_ih[0 * NH + j] + b_hh[0 * NH + j]);
            zbv[G][i] = dsc * (b_ih[1 * NH + j] + b_hh[1 * NH + j]);
            xbv[G][i] = csc * b_ih[2 * NH + j];   // x-part of n
            hbv[G][i] = csc * b_hh[2 * NH + j];   // h-part bias of n
        }
    }
    const float fcb = fc_b[0];
    float hold = 0.f;   // this lane's h row: jb + gs*16 + q*4 + (cl&3)

    const float* ubase = u + (size_t)b * NT * ND;
    float*       outb  = out + (size_t)b * NT;

    // ---- prologue: h0 = 0, fc_w to LDS, stage u16 chunk 0, prefetch chunk 1 ----
    if (tid < 64)  reinterpret_cast<unsigned int*>(hhist)[tid] = 0u;
    if (tid < NH)  fcw_lds[tid] = fc_w[tid];
    {
        float4 uv = *reinterpret_cast<const float4*>(ubase + 4 * tid);
        half8 hv;  // only 4 used; pack 4 halves via u64 store
        unsigned long long pk =
            (unsigned long long)__builtin_bit_cast(unsigned short, (_Float16)uv.x)
          | ((unsigned long long)__builtin_bit_cast(unsigned short, (_Float16)uv.y) << 16)
          | ((unsigned long long)__builtin_bit_cast(unsigned short, (_Float16)uv.z) << 32)
          | ((unsigned long long)__builtin_bit_cast(unsigned short, (_Float16)uv.w) << 48);
        reinterpret_cast<unsigned long long*>(u16)[tid] = pk;
        (void)hv;
    }
    float4 upre = *reinterpret_cast<const float4*>(ubase + SC * ND + 4 * tid);
    wg_barrier();

    for (int s = 0; s < NSC; ++s) {
        if (s > 0) {
            // fc flush for sub-chunk s-1 (reads hhist[1..SC]); 256 thr = 32 steps x 8 parts
            {
                const int tloc = tid >> 3;
                const int part = tid & 7;
                const _Float16* hp = hhist + (tloc + 1) * NH + part * 16;
                half8 h0 = *reinterpret_cast<const half8*>(hp);
                half8 h1 = *reinterpret_cast<const half8*>(hp + 8);
                float p = 0.f;
                #pragma unroll
                for (int i = 0; i < 8; ++i) p += (float)h0[i] * fcw_lds[part * 16 + i];
                #pragma unroll
                for (int i = 0; i < 8; ++i) p += (float)h1[i] * fcw_lds[part * 16 + 8 + i];
                p += __shfl_xor(p, 1);
                p += __shfl_xor(p, 2);
                p += __shfl_xor(p, 4);
                if (part == 0) outb[(s - 1) * SC + tloc] = p + fcb;
            }
            // carry h: hhist[SC] -> hhist[0]
            if (tid < 64) {
                unsigned int v = reinterpret_cast<const unsigned int*>(hhist + SC * NH)[tid];
                reinterpret_cast<unsigned int*>(hhist)[tid] = v;
            }
            // stage u16 for sub-chunk s (from prefetch), prefetch s+1
            {
                unsigned long long pk =
                    (unsigned long long)__builtin_bit_cast(unsigned short, (_Float16)upre.x)
                  | ((unsigned long long)__builtin_bit_cast(unsigned short, (_Float16)upre.y) << 16)
                  | ((unsigned long long)__builtin_bit_cast(unsigned short, (_Float16)upre.z) << 32)
                  | ((unsigned long long)__builtin_bit_cast(unsigned short, (_Float16)upre.w) << 48);
                reinterpret_cast<unsigned long long*>(u16)[tid] = pk;
            }
            if (s + 1 < NSC)
                upre = *reinterpret_cast<const float4*>(ubase + (size_t)(s + 1) * SC * ND + 4 * tid);
            wg_barrier();
        }

        // ---- recurrent rounds ----
        for (int tl = 0; tl < SC; ++tl) {
            // B-fragments: h (4 k-chunks) + u_t, broadcast across the 16 cl lanes
            const _Float16* hrow = hhist + tl * NH + q * 8;
            half8 bh0 = *reinterpret_cast<const half8*>(hrow + 0 * 32);
            half8 bh1 = *reinterpret_cast<const half8*>(hrow + 1 * 32);
            half8 bh2 = *reinterpret_cast<const half8*>(hrow + 2 * 32);
            half8 bh3 = *reinterpret_cast<const half8*>(hrow + 3 * 32);
            half8 bu  = *reinterpret_cast<const half8*>(&u16[tl * ND + q * 8]);

            floatx4 rA = rbv[0], zA = zbv[0], hA = hbv[0], xA = xbv[0];
            floatx4 rB = rbv[1], zB = zbv[1], hB = hbv[1], xB = xbv[1];

            // k-chunk 0
            rA = __builtin_amdgcn_mfma_f32_16x16x32_f16(aR[0][0], bh0, rA, 0, 0, 0);
            rB = __builtin_amdgcn_mfma_f32_16x16x32_f16(aR[1][0], bh0, rB, 0, 0, 0);
            zA = __builtin_amdgcn_mfma_f32_16x16x32_f16(aZ[0][0], bh0, zA, 0, 0, 0);
            zB = __builtin_amdgcn_mfma_f32_16x16x32_f16(aZ[1][0], bh0, zB, 0, 0, 0);
            hA = __builtin_amdgcn_mfma_f32_16x16x32_f16(aN[0][0], bh0, hA, 0, 0, 0);
            hB = __builtin_amdgcn_mfma_f32_16x16x32_f16(aN[1][0], bh0, hB, 0, 0, 0);
            // k-chunk 1
            rA = __builtin_amdgcn_mfma_f32_16x16x32_f16(aR[0][1], bh1, rA, 0, 0, 0);
            rB = __builtin_amdgcn_mfma_f32_16x16x32_f16(aR[1][1], bh1, rB, 0, 0, 0);
            zA = __builtin_amdgcn_mfma_f32_16x16x32_f16(aZ[0][1], bh1, zA, 0, 0, 0);
            zB = __builtin_amdgcn_mfma_f32_16x16x32_f16(aZ[1][1], bh1, zB, 0, 0, 0);
            hA = __builtin_amdgcn_mfma_f32_16x16x32_f16(aN[0][1], bh1, hA, 0, 0, 0);
            hB = __builtin_amdgcn_mfma_f32_16x16x32_f16(aN[1][1], bh1, hB, 0, 0, 0);
            // k-chunk 2
            rA = __builtin_amdgcn_mfma_f32_16x16x32_f16(aR[0][2], bh2, rA, 0, 0, 0);
            rB = __builtin_amdgcn_mfma_f32_16x16x32_f16(aR[1][2], bh2, rB, 0, 0, 0);
            zA = __builtin_amdgcn_mfma_f32_16x16x32_f16(aZ[0][2], bh2, zA, 0, 0, 0);
            zB = __builtin_amdgcn_mfma_f32_16x16x32_f16(aZ[1][2], bh2, zB, 0, 0, 0);
            hA = __builtin_amdgcn_mfma_f32_16x16x32_f16(aN[0][2], bh2, hA, 0, 0, 0);
            hB = __builtin_amdgcn_mfma_f32_16x16x32_f16(aN[1][2], bh2, hB, 0, 0, 0);
            // k-chunk 3
            rA = __builtin_amdgcn_mfma_f32_16x16x32_f16(aR[0][3], bh3, rA, 0, 0, 0);
            rB = __builtin_amdgcn_mfma_f32_16x16x32_f16(aR[1][3], bh3, rB, 0, 0, 0);
            zA = __builtin_amdgcn_mfma_f32_16x16x32_f16(aZ[0][3], bh3, zA, 0, 0, 0);
            zB = __builtin_amdgcn_mfma_f32_16x16x32_f16(aZ[1][3], bh3, zB, 0, 0, 0);
            hA = __builtin_amdgcn_mfma_f32_16x16x32_f16(aN[0][3], bh3, hA, 0, 0, 0);
            hB = __builtin_amdgcn_mfma_f32_16x16x32_f16(aN[1][3], bh3, hB, 0, 0, 0);
            // u-chunk (K=32): finishes r/z (K=160 total); xn is u-only
            rA = __builtin_amdgcn_mfma_f32_16x16x32_f16(aR[0][4], bu, rA, 0, 0, 0);
            rB = __builtin_amdgcn_mfma_f32_16x16x32_f16(aR[1][4], bu, rB, 0, 0, 0);
            zA = __builtin_amdgcn_mfma_f32_16x16x32_f16(aZ[0][4], bu, zA, 0, 0, 0);
            zB = __builtin_amdgcn_mfma_f32_16x16x32_f16(aZ[1][4], bu, zB, 0, 0, 0);
            xA = __builtin_amdgcn_mfma_f32_16x16x32_f16(aX[0],    bu, xA, 0, 0, 0);
            xB = __builtin_amdgcn_mfma_f32_16x16x32_f16(aX[1],    bu, xB, 0, 0, 0);

            // gate math: lane handles unit (cl&3) of group gs
            const float pre_r = gs ? sel4(rB, s0, s1) : sel4(rA, s0, s1);
            const float pre_z = gs ? sel4(zB, s0, s1) : sel4(zA, s0, s1);
            const float pre_h = gs ? sel4(hB, s0, s1) : sel4(hA, s0, s1);
            const float pre_x = gs ? sel4(xB, s0, s1) : sel4(xA, s0, s1);
            const float rg = __builtin_amdgcn_rcpf(1.0f + __builtin_amdgcn_exp2f(pre_r));
            const float zg = __builtin_amdgcn_rcpf(1.0f + __builtin_amdgcn_exp2f(pre_z));
            const float zh = zg * hold;                     // off the ng critical path
            const float ng = 1.0f - 2.0f * __builtin_amdgcn_rcpf(
                                 1.0f + __builtin_amdgcn_exp2f(pre_x + rg * pre_h));
            const float h  = ng - zg * ng + zh;
            hold = h;

            if (cl < 8)  // one writer per row: row = jb + (cl>>2)*16 + q*4 + (cl&3)
                hhist[(tl + 1) * NH + jb + (cl >> 2) * 16 + q * 4 + (cl & 3)] = (_Float16)h;
            wg_barrier();
        }
    }

    // final fc flush (sub-chunk NSC-1)
    {
        const int tloc = tid >> 3;
        const int part = tid & 7;
        const _Float16* hp = hhist + (tloc + 1) * NH + part * 16;
        half8 h0 = *reinterpret_cast<const half8*>(hp);
        half8 h1 = *reinterpret_cast<const half8*>(hp + 8);
        float p = 0.f;
        #pragma unroll
        for (int i = 0; i < 8; ++i) p += (float)h0[i] * fcw_lds[part * 16 + i];
        #pragma unroll
        for (int i = 0; i < 8; ++i) p += (float)h1[i] * fcw_lds[part * 16 + 8 + i];
        p += __shfl_xor(p, 1);
        p += __shfl_xor(p, 2);
        p += __shfl_xor(p, 4);
        if (part == 0) outb[(NSC - 1) * SC + tloc] = p + fcb;
    }
}

extern "C" void kernel_launch(void* const* d_in, const int* in_sizes, int n_in,
                              void* d_out, int out_size, void* d_ws, size_t ws_size,
                              hipStream_t stream)
{
    const float* u    = (const float*)d_in[0];
    const float* w_ih = (const float*)d_in[1];
    const float* w_hh = (const float*)d_in[2];
    const float* b_ih = (const float*)d_in[3];
    const float* b_hh = (const float*)d_in[4];
    const float* fc_w = (const float*)d_in[5];
    const float* fc_b = (const float*)d_in[6];

    gru_fused_kernel<<<dim3(NB), dim3(256), 0, stream>>>(
        u, w_ih, w_hh, b_ih, b_hh, fc_w, fc_b, (float*)d_out);
}

// Round 5
// 1681.278 us; speedup vs baseline: 1.0906x; 1.0906x over previous
//
#include <hip/hip_runtime.h>

#define NB 64
#define NT 4096
#define ND 32
#define NH 128
#define SC 32                    // steps per sub-chunk
#define NSC (NT / SC)            // 128 sub-chunks

typedef _Float16 half8 __attribute__((ext_vector_type(8)));
typedef float floatx4 __attribute__((ext_vector_type(4)));

// s_barrier WITHOUT vmcnt drain: orders LDS only (all cross-wave data is LDS).
// Lets u-prefetch global loads stay in flight across step barriers.
__device__ __forceinline__ void wg_barrier() {
    asm volatile("s_waitcnt lgkmcnt(0)\n\ts_barrier" ::: "memory");
}

// constant-indexed 4:1 mux
__device__ __forceinline__ float sel4(floatx4 v, bool b0, bool b1) {
    float s0 = b0 ? v[1] : v[0];
    float s1 = b0 ? v[3] : v[2];
    return b1 ? s1 : s0;
}

// One workgroup (512 thr = 8 waves, 2 waves/SIMD for latency overlap) per batch.
// Wave w owns hidden rows [16w, 16w+16). Per step: 5 ds_read_b128 (4x h + 1x u)
// -> 15 MFMA (r: K=160 as 2+3-deep split chains; z: K=160 5-deep off-critical;
// n-h: K=128 as 2+2-deep; xn: K=32) -> per-lane gate unit (cl&3, 12 cndmask)
// -> 1 ds_write_b16 -> LDS-only barrier. fc + u-staging batched per 32 steps.
// Weights prescaled: r/z by -log2e (sigmoid = rcp(1+exp2(s))),
//                    n   by 2*log2e (tanh = 1-2*rcp(1+exp2(s))).
__global__ void __launch_bounds__(512, 2) gru_fused_kernel(
    const float* __restrict__ u,
    const float* __restrict__ w_ih,
    const float* __restrict__ w_hh,
    const float* __restrict__ b_ih,
    const float* __restrict__ b_hh,
    const float* __restrict__ fc_w,
    const float* __restrict__ fc_b,
    float* __restrict__ out)
{
    __shared__ __align__(16) _Float16 hhist[(SC + 1) * NH];   // 8.25 KB h history
    __shared__ __align__(16) _Float16 u16[SC * ND];           // 2 KB f16 input sub-chunk
    __shared__ float fcw_lds[NH];                             // 0.5 KB

    const int tid = (int)threadIdx.x;
    const int b   = (int)blockIdx.x;
    const int w   = tid >> 6;   // wave 0..7
    const int l   = tid & 63;   // lane
    const int q   = l >> 4;     // lane quad-group 0..3
    const int cl  = l & 15;     // A-row / B-col / C-col within tile
    const int jb  = w * 16;     // this wave's hidden-row base
    const bool s0 = (cl & 1) != 0;   // gate-unit select (unit = cl&3)
    const bool s1 = (cl & 2) != 0;

    const float dsc = -1.44269504089f;  // -log2(e)
    const float csc =  2.88539008178f;  // 2*log2(e)

    // ---- weight A-fragments, prescaled. A[row=cl][k = chunk*32 + q*8 + i] ----
    // aR[0..3] = dsc*W_hr k-chunks, aR[4] = dsc*W_ir (u-part, K=32)
    // aZ[0..3] = dsc*W_hz,          aZ[4] = dsc*W_iz
    // aN[0..3] = csc*W_hn,          aX    = csc*W_in
    half8 aR[5], aZ[5], aN[4], aX;
    #pragma unroll
    for (int c = 0; c < 4; ++c) {
        const float* pr = w_hh + (size_t)(0 * NH + jb + cl) * NH + c * 32 + q * 8;
        const float* pz = w_hh + (size_t)(1 * NH + jb + cl) * NH + c * 32 + q * 8;
        const float* pn = w_hh + (size_t)(2 * NH + jb + cl) * NH + c * 32 + q * 8;
        #pragma unroll
        for (int i = 0; i < 8; ++i) {
            aR[c][i] = (_Float16)(dsc * pr[i]);
            aZ[c][i] = (_Float16)(dsc * pz[i]);
            aN[c][i] = (_Float16)(csc * pn[i]);
        }
    }
    {
        const float* pr = w_ih + (size_t)(0 * NH + jb + cl) * ND + q * 8;
        const float* pz = w_ih + (size_t)(1 * NH + jb + cl) * ND + q * 8;
        const float* pn = w_ih + (size_t)(2 * NH + jb + cl) * ND + q * 8;
        #pragma unroll
        for (int i = 0; i < 8; ++i) {
            aR[4][i] = (_Float16)(dsc * pr[i]);
            aZ[4][i] = (_Float16)(dsc * pz[i]);
            aX[i]    = (_Float16)(csc * pn[i]);
        }
    }

    // Prescaled bias quads (C rows j = jb + q*4 + i).
    floatx4 rbv, zbv, xbv, hbv;
    #pragma unroll
    for (int i = 0; i < 4; ++i) {
        const int j = jb + q * 4 + i;
        rbv[i] = dsc * (b_ih[0 * NH + j] + b_hh[0 * NH + j]);
        zbv[i] = dsc * (b_ih[1 * NH + j] + b_hh[1 * NH + j]);
        xbv[i] = csc * b_ih[2 * NH + j];   // x-part of n
        hbv[i] = csc * b_hh[2 * NH + j];   // h-part bias of n
    }
    const float fcb = fc_b[0];
    float hold = 0.f;   // this lane's h row: jb + q*4 + (cl&3)
    const floatx4 zero4 = {0.f, 0.f, 0.f, 0.f};

    const float* ubase = u + (size_t)b * NT * ND;
    float*       outb  = out + (size_t)b * NT;

    // ---- prologue: h0 = 0, fc_w to LDS, stage u16 chunk 0, prefetch chunk 1 ----
    if (tid < 64)  reinterpret_cast<unsigned int*>(hhist)[tid] = 0u;
    if (tid < NH)  fcw_lds[tid] = fc_w[tid];
    {
        float2 uv = *reinterpret_cast<const float2*>(ubase + 2 * tid);
        unsigned int pk =
            (unsigned int)__builtin_bit_cast(unsigned short, (_Float16)uv.x)
          | ((unsigned int)__builtin_bit_cast(unsigned short, (_Float16)uv.y) << 16);
        reinterpret_cast<unsigned int*>(u16)[tid] = pk;
    }
    float2 upre = *reinterpret_cast<const float2*>(ubase + SC * ND + 2 * tid);
    wg_barrier();

    for (int s = 0; s < NSC; ++s) {
        if (s > 0) {
            // fc flush for sub-chunk s-1 (reads hhist[1..SC]); 256 thr = 32 steps x 8 parts
            if (tid < 256) {
                const int tloc = tid >> 3;
                const int part = tid & 7;
                const _Float16* hp = hhist + (tloc + 1) * NH + part * 16;
                half8 h0 = *reinterpret_cast<const half8*>(hp);
                half8 h1 = *reinterpret_cast<const half8*>(hp + 8);
                float p = 0.f;
                #pragma unroll
                for (int i = 0; i < 8; ++i) p += (float)h0[i] * fcw_lds[part * 16 + i];
                #pragma unroll
                for (int i = 0; i < 8; ++i) p += (float)h1[i] * fcw_lds[part * 16 + 8 + i];
                p += __shfl_xor(p, 1);
                p += __shfl_xor(p, 2);
                p += __shfl_xor(p, 4);
                if (part == 0) outb[(s - 1) * SC + tloc] = p + fcb;
            }
            // carry h: hhist[SC] -> hhist[0]
            if (tid < 64) {
                unsigned int v = reinterpret_cast<const unsigned int*>(hhist + SC * NH)[tid];
                reinterpret_cast<unsigned int*>(hhist)[tid] = v;
            }
            // stage u16 for sub-chunk s (from prefetch), prefetch s+1
            {
                unsigned int pk =
                    (unsigned int)__builtin_bit_cast(unsigned short, (_Float16)upre.x)
                  | ((unsigned int)__builtin_bit_cast(unsigned short, (_Float16)upre.y) << 16);
                reinterpret_cast<unsigned int*>(u16)[tid] = pk;
            }
            if (s + 1 < NSC)
                upre = *reinterpret_cast<const float2*>(ubase + (size_t)(s + 1) * SC * ND + 2 * tid);
            wg_barrier();
        }

        // ---- recurrent steps ----
        for (int tl = 0; tl < SC; ++tl) {
            // B-fragments: h (4 k-chunks) + u_t, broadcast across the 16 cl lanes
            const _Float16* hrow = hhist + tl * NH + q * 8;
            half8 bh0 = *reinterpret_cast<const half8*>(hrow + 0 * 32);
            half8 bh2 = *reinterpret_cast<const half8*>(hrow + 2 * 32);
            half8 bh1 = *reinterpret_cast<const half8*>(hrow + 1 * 32);
            half8 bh3 = *reinterpret_cast<const half8*>(hrow + 3 * 32);
            half8 bu  = *reinterpret_cast<const half8*>(&u16[tl * ND + q * 8]);

            // split accumulator chains; same-accumulator spacing >= 3 MFMA slots
            floatx4 r1 = rbv, z1 = zbv, h1 = hbv, x1 = xbv;
            floatx4 r2 = zero4, h2 = zero4;

            r1 = __builtin_amdgcn_mfma_f32_16x16x32_f16(aR[0], bh0, r1, 0, 0, 0);  // 1
            z1 = __builtin_amdgcn_mfma_f32_16x16x32_f16(aZ[0], bh0, z1, 0, 0, 0);  // 2
            h1 = __builtin_amdgcn_mfma_f32_16x16x32_f16(aN[0], bh0, h1, 0, 0, 0);  // 3
            r2 = __builtin_amdgcn_mfma_f32_16x16x32_f16(aR[2], bh2, r2, 0, 0, 0);  // 4
            z1 = __builtin_amdgcn_mfma_f32_16x16x32_f16(aZ[1], bh1, z1, 0, 0, 0);  // 5
            h2 = __builtin_amdgcn_mfma_f32_16x16x32_f16(aN[2], bh2, h2, 0, 0, 0);  // 6
            r1 = __builtin_amdgcn_mfma_f32_16x16x32_f16(aR[1], bh1, r1, 0, 0, 0);  // 7
            z1 = __builtin_amdgcn_mfma_f32_16x16x32_f16(aZ[2], bh2, z1, 0, 0, 0);  // 8
            h1 = __builtin_amdgcn_mfma_f32_16x16x32_f16(aN[1], bh1, h1, 0, 0, 0);  // 9
            r2 = __builtin_amdgcn_mfma_f32_16x16x32_f16(aR[3], bh3, r2, 0, 0, 0);  // 10
            z1 = __builtin_amdgcn_mfma_f32_16x16x32_f16(aZ[3], bh3, z1, 0, 0, 0);  // 11
            h2 = __builtin_amdgcn_mfma_f32_16x16x32_f16(aN[3], bh3, h2, 0, 0, 0);  // 12
            x1 = __builtin_amdgcn_mfma_f32_16x16x32_f16(aX,    bu, x1, 0, 0, 0);   // 13
            z1 = __builtin_amdgcn_mfma_f32_16x16x32_f16(aZ[4], bu, z1, 0, 0, 0);   // 14
            r2 = __builtin_amdgcn_mfma_f32_16x16x32_f16(aR[4], bu, r2, 0, 0, 0);   // 15

            // gate math: this lane handles only unit (cl&3); 6 sel-pairs = 12 cndmask... (r,h split: +2 adds)
            const float pre_r = sel4(r1, s0, s1) + sel4(r2, s0, s1);
            const float pre_h = sel4(h1, s0, s1) + sel4(h2, s0, s1);
            const float pre_x = sel4(x1, s0, s1);
            const float pre_z = sel4(z1, s0, s1);
            const float rg = __builtin_amdgcn_rcpf(1.0f + __builtin_amdgcn_exp2f(pre_r));
            const float zg = __builtin_amdgcn_rcpf(1.0f + __builtin_amdgcn_exp2f(pre_z));
            const float zh = zg * hold;                     // off the ng critical path
            const float ng = 1.0f - 2.0f * __builtin_amdgcn_rcpf(
                                 1.0f + __builtin_amdgcn_exp2f(pre_x + rg * pre_h));
            const float h  = ng - zg * ng + zh;
            hold = h;

            if (cl < 4)  // one writer per row: row = jb + q*4 + cl
                hhist[(tl + 1) * NH + jb + q * 4 + cl] = (_Float16)h;
            wg_barrier();
        }
    }

    // final fc flush (sub-chunk NSC-1)
    if (tid < 256) {
        const int tloc = tid >> 3;
        const int part = tid & 7;
        const _Float16* hp = hhist + (tloc + 1) * NH + part * 16;
        half8 h0 = *reinterpret_cast<const half8*>(hp);
        half8 h1 = *reinterpret_cast<const half8*>(hp + 8);
        float p = 0.f;
        #pragma unroll
        for (int i = 0; i < 8; ++i) p += (float)h0[i] * fcw_lds[part * 16 + i];
        #pragma unroll
        for (int i = 0; i < 8; ++i) p += (float)h1[i] * fcw_lds[part * 16 + 8 + i];
        p += __shfl_xor(p, 1);
        p += __shfl_xor(p, 2);
        p += __shfl_xor(p, 4);
        if (part == 0) outb[(NSC - 1) * SC + tloc] = p + fcb;
    }
}

extern "C" void kernel_launch(void* const* d_in, const int* in_sizes, int n_in,
                              void* d_out, int out_size, void* d_ws, size_t ws_size,
                              hipStream_t stream)
{
    const float* u    = (const float*)d_in[0];
    const float* w_ih = (const float*)d_in[1];
    const float* w_hh = (const float*)d_in[2];
    const float* b_ih = (const float*)d_in[3];
    const float* b_hh = (const float*)d_in[4];
    const float* fc_w = (const float*)d_in[5];
    const float* fc_b = (const float*)d_in[6];

    gru_fused_kernel<<<dim3(NB), dim3(512), 0, stream>>>(
        u, w_ih, w_hh, b_ih, b_hh, fc_w, fc_b, (float*)d_out);
}